// Round 2
// baseline (234.176 us; speedup 1.0000x reference)
//
#include <hip/hip_runtime.h>

#define HID   768
#define BATCH 4
#define SEQ   128
#define NROWS 512
#define PAIRS_PER_MAT (NROWS * (HID/2))

typedef __bf16 bf16x8 __attribute__((ext_vector_type(8)));
typedef float  floatx4 __attribute__((ext_vector_type(4)));

__device__ __forceinline__ unsigned short f2bf(float x) {   // RNE f32->bf16, finite only
    unsigned u = __builtin_bit_cast(unsigned, x);
    unsigned r = u + 0x7FFFu + ((u >> 16) & 1u);
    return (unsigned short)(r >> 16);
}

// ---- kernel 1: rotary (f32 in) -> bf16 rot buffer [2][512][768] ----
__global__ __launch_bounds__(256) void rotary_kernel(
    const float* __restrict__ review,
    const float* __restrict__ reply,
    unsigned short* __restrict__ rot)
{
    int p   = blockIdx.x * 256 + threadIdx.x;
    int mat = (p >= PAIRS_PER_MAT) ? 1 : 0;
    int rem = p - mat * PAIRS_PER_MAT;
    int row = rem / (HID / 2);
    int i   = rem - row * (HID / 2);
    int s   = row & 127;

    const float* src = (mat ? reply : review) + row * HID + 2 * i;
    float2 x = *reinterpret_cast<const float2*>(src);

    float inv = exp2f(-(float)i * (13.287712379549449f / 384.0f)); // 10000^(-i/384)
    float ang = (float)s * inv;
    float c  = cosf(ang);
    float sn = sinf(ang);

    float oe = x.x * c - x.y * sn;
    float oo = x.y * c + x.x * sn;
    unsigned pk = (unsigned)f2bf(oe) | ((unsigned)f2bf(oo) << 16);
    *reinterpret_cast<unsigned*>(rot + (size_t)mat * (NROWS * HID) + row * HID + 2 * i) = pk;
}

// ---- kernel 2: proj[mat][row][o] = sum_h rot[mat][row][h] * W[o][mat*768 + h]
// (einsum 'bnh,oh': W_x[o][h] = W[o*1536 + mat*768 + h], contiguous along h)
__global__ __launch_bounds__(256) void gemm_kernel(
    const unsigned short* __restrict__ rot,
    const float* __restrict__ W,              // [768][1536] f32
    float* __restrict__ proj)                 // [2][512][768] f32
{
    __shared__ __align__(16) unsigned short As[64 * 32];
    __shared__ __align__(16) unsigned short Bs[64 * 32];   // Bs[o_local][k] bf16

    const int tid  = threadIdx.x;
    const int lane = tid & 63;
    const int wave = tid >> 6;
    const int mat  = blockIdx.z;
    const int row0 = blockIdx.y * 64;
    const int col0 = blockIdx.x * 64;
    const int q    = lane >> 4;
    const int r16  = lane & 15;

    const unsigned short* Abase = rot + (size_t)mat * (NROWS * HID);
    const int srow  = tid >> 2;           // 0..63
    const int skoff = (tid & 3) * 8;      // 0,8,16,24

    floatx4 acc[4];
#pragma unroll
    for (int c = 0; c < 4; ++c) acc[c] = (floatx4)0.0f;

    for (int k0 = 0; k0 < HID; k0 += 32) {
        __syncthreads();
        *reinterpret_cast<uint4*>(&As[srow * 32 + skoff]) =
            *reinterpret_cast<const uint4*>(&Abase[(row0 + srow) * HID + k0 + skoff]);
        {
            // B[o][k] = W[(col0+srow)*1536 + mat*768 + k0+skoff + 0..7]  (contiguous f32)
            const float* wp = W + (size_t)(col0 + srow) * (2 * HID) + mat * HID + k0 + skoff;
            float4 w0 = *reinterpret_cast<const float4*>(wp);
            float4 w1 = *reinterpret_cast<const float4*>(wp + 4);
            uint4 pk;
            pk.x = (unsigned)f2bf(w0.x) | ((unsigned)f2bf(w0.y) << 16);
            pk.y = (unsigned)f2bf(w0.z) | ((unsigned)f2bf(w0.w) << 16);
            pk.z = (unsigned)f2bf(w1.x) | ((unsigned)f2bf(w1.y) << 16);
            pk.w = (unsigned)f2bf(w1.z) | ((unsigned)f2bf(w1.w) << 16);
            *reinterpret_cast<uint4*>(&Bs[srow * 32 + skoff]) = pk;
        }
        __syncthreads();

        bf16x8 af = *reinterpret_cast<const bf16x8*>(&As[(wave * 16 + r16) * 32 + q * 8]);
#pragma unroll
        for (int c = 0; c < 4; ++c) {
            bf16x8 bf = *reinterpret_cast<const bf16x8*>(&Bs[(c * 16 + r16) * 32 + q * 8]);
            acc[c] = __builtin_amdgcn_mfma_f32_16x16x32_bf16(af, bf, acc[c], 0, 0, 0);
        }
    }

    // C/D layout: col = lane&15, row = (lane>>4)*4 + reg
    float* pbase = proj + (size_t)mat * (NROWS * HID);
#pragma unroll
    for (int c = 0; c < 4; ++c) {
        int col = col0 + c * 16 + r16;
#pragma unroll
        for (int rg = 0; rg < 4; ++rg) {
            int row = row0 + wave * 16 + q * 4 + rg;
            pbase[row * HID + col] = acc[c][rg];
        }
    }
}

// ---- kernel 3: out[b,n,m,o] = relu(pr[b,n,o] + pp[b,m,o] + bias[o]) -> f32 ----
__global__ __launch_bounds__(256) void bcast_kernel(
    const float* __restrict__ proj,
    const float* __restrict__ bias,
    float* __restrict__ out)
{
    const int bn = blockIdx.x;
    const int b  = bn >> 7;

    __shared__ __align__(16) float prb[HID];
    const float* pr  = proj + (size_t)bn * HID;
    const float* ppb = proj + (size_t)(NROWS + b * SEQ) * HID;
    for (int o = threadIdx.x; o < HID; o += 256)
        prb[o] = pr[o] + bias[o];
    __syncthreads();

    float* obase = out + (size_t)bn * (SEQ * HID);
    for (int it = 0; it < 96; ++it) {
        int idx = it * 256 + threadIdx.x;      // 0..24575
        int m   = idx / 192;
        int t   = idx - m * 192;
        int o4  = t * 4;

        float4 p = *reinterpret_cast<const float4*>(ppb + m * HID + o4);
        float4 a = *reinterpret_cast<const float4*>(&prb[o4]);
        float4 r;
        r.x = fmaxf(a.x + p.x, 0.0f);
        r.y = fmaxf(a.y + p.y, 0.0f);
        r.z = fmaxf(a.z + p.z, 0.0f);
        r.w = fmaxf(a.w + p.w, 0.0f);
        *reinterpret_cast<float4*>(obase + m * HID + o4) = r;
    }
}

extern "C" void kernel_launch(void* const* d_in, const int* in_sizes, int n_in,
                              void* d_out, int out_size, void* d_ws, size_t ws_size,
                              hipStream_t stream) {
    const float* review = (const float*)d_in[0];
    const float* reply  = (const float*)d_in[1];
    const float* W      = (const float*)d_in[2];
    const float* bias   = (const float*)d_in[3];
    float* out = (float*)d_out;

    unsigned short* rot = (unsigned short*)d_ws;
    float* proj = (float*)((char*)d_ws + (size_t)2 * NROWS * HID * sizeof(unsigned short));

    rotary_kernel<<<PAIRS_PER_MAT * 2 / 256, 256, 0, stream>>>(review, reply, rot);
    dim3 g2(HID / 64, NROWS / 64, 2);
    gemm_kernel<<<g2, 256, 0, stream>>>(rot, W, proj);
    bcast_kernel<<<NROWS, 256, 0, stream>>>(proj, bias, out);
}